// Round 3
// baseline (124.952 us; speedup 1.0000x reference)
//
#include <hip/hip_runtime.h>

#define RADIUS 5
#define WIN 9
#define BB 4
#define KK 4
#define HH 224
#define WW 224
#define HW (HH * WW)
#define PD 234                 // HH + 2*RADIUS
#define PAREA (PD * PD)        // 54756
#define NBUCKET 64
#define PARTIAL_FLOATS (NBUCKET * BB * 8)   // 2048 floats
#define WAVES_PER_B (HW / 64)               // 784 waves of 64 px per batch
#define ELEMS_PER_WAVE (64 * 81)            // 5184

// d_ws layout (floats):
//   [0, 2048)                : partial buckets [bucket][b][8] (0..3 A_k, 4..7 V_k)
//   [2048, ...)              : padded seg P[b][r][c][k] as float4 per (r,c)

// ---------- pre-pass: seg [B,K,H,W] -> zero-padded [B,PD,PD,K] (float4) ----------
__global__ __launch_bounds__(256) void ncuts_pad(
    const float* __restrict__ seg, float4* __restrict__ pseg)
{
    const int tid = blockIdx.x * 256 + threadIdx.x;
    if (tid >= BB * PAREA) return;
    const int b  = tid / PAREA;
    const int rc = tid - b * PAREA;
    const int r  = rc / PD;
    const int c  = rc - r * PD;
    const int hh = r - RADIUS;
    const int ww = c - RADIUS;
    float4 v = {0.f, 0.f, 0.f, 0.f};
    if (hh >= 0 && hh < HH && ww >= 0 && ww < WW) {
        const float* sb = seg + (size_t)b * KK * HW + hh * WW + ww;
        v.x = sb[0 * HW];
        v.y = sb[1 * HW];
        v.z = sb[2 * HW];
        v.w = sb[3 * HW];
    }
    pseg[tid] = v;
}

// ---------- main: tap-parallel, weight read in native flat order ----------
// wave g handles weight elements [g*5184, (g+1)*5184) = pixels [g*64, g*64+64) x 81 taps.
// iteration t: lane L handles element t*64 + L.
__global__ __launch_bounds__(256, 4) void ncuts_main(
    const float* __restrict__ weight,
    const float4* __restrict__ pseg,
    float* __restrict__ partial)
{
    const int lane = threadIdx.x & 63;
    const int wid  = blockIdx.x * 4 + (threadIdx.x >> 6);  // global wave id, 0..3135
    const int b    = wid / WAVES_PER_B;                    // uniform per block

    const float* wbase = weight + (size_t)wid * ELEMS_PER_WAVE;
    const float4* p4   = pseg + (size_t)b * PAREA;

    // per-lane state: starting pixel = wid*64 (same for all lanes), tap = lane
    const int pix0 = wid * 64;
    const int rem0 = pix0 - b * HW;
    int h = rem0 / WW;
    int w = rem0 - h * WW;          // uniform start; diverges per lane as taps wrap
    int rowoff = h * PD + w;        // index into p4 of (h, w) corner
    int tap = lane;

    float a0 = 0.f, a1 = 0.f, a2 = 0.f, a3 = 0.f;
    float v0 = 0.f, v1 = 0.f, v2 = 0.f, v3 = 0.f;

    #pragma unroll 3
    for (int t = 0; t < 81; ++t) {
        const float wv = wbase[t * 64 + lane];

        const int m = (tap * 57) >> 9;      // tap / 9, exact for tap < 81
        const int n = tap - 9 * m;

        const float4 s = p4[rowoff + m * PD + n];          // pad tap (L1/L2 hit)
        const float4 o = p4[rowoff + (RADIUS * PD + RADIUS)]; // own pixel (broadcast)

        a0 = fmaf(wv * s.x, o.x, a0);
        a1 = fmaf(wv * s.y, o.y, a1);
        a2 = fmaf(wv * s.z, o.z, a2);
        a3 = fmaf(wv * s.w, o.w, a3);
        v0 = fmaf(wv, o.x, v0);
        v1 = fmaf(wv, o.y, v1);
        v2 = fmaf(wv, o.z, v2);
        v3 = fmaf(wv, o.w, v3);

        // advance element by 64: tap wraps at most once; pixel++ iff wrap
        const int t2 = tap + 64;
        const bool wrap = (t2 >= 81);
        tap = wrap ? t2 - 81 : t2;
        if (wrap) {
            const bool roww = (w == WW - 1);
            w = roww ? 0 : w + 1;
            rowoff += roww ? (PD - WW + 1) : 1;   // new row: +PD-223, else +1
        }
    }

    float vals[8] = { a0, a1, a2, a3, v0, v1, v2, v3 };

    #pragma unroll
    for (int i = 0; i < 8; ++i) {
        float v = vals[i];
        v += __shfl_down(v, 32);
        v += __shfl_down(v, 16);
        v += __shfl_down(v, 8);
        v += __shfl_down(v, 4);
        v += __shfl_down(v, 2);
        v += __shfl_down(v, 1);
        vals[i] = v;
    }

    if (lane == 0) {
        const int bucket = wid & (NBUCKET - 1);
        float* dst = partial + (bucket * BB + b) * 8;
        #pragma unroll
        for (int i = 0; i < 8; ++i)
            atomicAdd(dst + i, vals[i]);
    }
}

// ---------- final: fold buckets, compute loss ----------
__global__ __launch_bounds__(64) void ncuts_final(
    const float* __restrict__ partial, float* __restrict__ out)
{
    __shared__ float sums[32];
    const int t = threadIdx.x;
    if (t < 32) {
        const int b = t >> 3;
        const int i = t & 7;
        float s = 0.f;
        for (int bucket = 0; bucket < NBUCKET; ++bucket)
            s += partial[(bucket * BB + b) * 8 + i];
        sums[b * 8 + i] = s;
    }
    __syncthreads();
    if (t == 0) {
        float total = 0.f;
        for (int b = 0; b < BB; ++b) {
            float assoc = 0.f;
            for (int k = 0; k < KK; ++k) {
                const float A = sums[b * 8 + k];
                const float V = sums[b * 8 + 4 + k];
                assoc += A / V;
            }
            total += (float)KK - assoc;
        }
        out[0] = total;
    }
}

extern "C" void kernel_launch(void* const* d_in, const int* in_sizes, int n_in,
                              void* d_out, int out_size, void* d_ws, size_t ws_size,
                              hipStream_t stream) {
    const float* seg    = (const float*)d_in[0];
    const float* weight = (const float*)d_in[1];
    float* out     = (float*)d_out;
    float* wsf     = (float*)d_ws;
    float* partial = wsf;
    float4* pseg   = (float4*)(wsf + PARTIAL_FLOATS);   // 16B-aligned

    hipMemsetAsync(d_ws, 0, PARTIAL_FLOATS * sizeof(float), stream);

    {
        const int total = BB * PAREA;           // 219024
        const int grid  = (total + 255) / 256;  // 856
        hipLaunchKernelGGL(ncuts_pad, dim3(grid), dim3(256), 0, stream, seg, pseg);
    }
    {
        const int grid = (BB * WAVES_PER_B) / 4;  // 784 blocks x 4 waves
        hipLaunchKernelGGL(ncuts_main, dim3(grid), dim3(256), 0, stream,
                           weight, pseg, partial);
    }
    hipLaunchKernelGGL(ncuts_final, dim3(1), dim3(64), 0, stream, partial, out);
}